// Round 7
// baseline (451.773 us; speedup 1.0000x reference)
//
#include <hip/hip_runtime.h>
#include <math.h>

// SimpleGCN R19 = R18 (259.9us, edge-parallel int-ds_add agg) + two fixes
// driven by R18 counters.
//  - k_dinv_gemm was top kernel (58-65us, occ 8%, VGPR 148): fused
//    degree-count + 64-row GEMM starved at 782 blocks with serial phase
//    chain. Split: tiny k_dinv (782 blocks) + R12's proven k_gemm_scale
//    (3125 blocks, never in any top-5).
//  - agg1/agg2 (~50us each by wall math) run at only ~12 waves/CU
//    (782 blocks x 4 waves). Now 512 threads/block (8 waves, ~24 waves/CU):
//    same LDS, same per-edge instruction shape (128-edge windows),
//    epilogue spread over 8 waves.
//  - 8 dispatches: hist, scan, scatter, dinv, gemm1, agg1, agg2, readout.

#define CH 4096
#define MAXNB 1024
#define SCL 2097152.0f            // 2^21
#define INVSCL 4.76837158203125e-7f

__device__ __forceinline__ float bf2f(unsigned short u) {
    return __uint_as_float(((unsigned)u) << 16);
}
__device__ __forceinline__ unsigned short f2bf(float x) {
    unsigned b = __float_as_uint(x);
    return (unsigned short)((b + 0x7FFF + ((b >> 16) & 1)) >> 16);  // RNE
}

__global__ __launch_bounds__(256) void k_bucket_hist(const int* __restrict__ dst,
                                                     int* __restrict__ histmat,
                                                     int E, int NB) {
    __shared__ int ih[MAXNB];
    int t = threadIdx.x;
    for (int k = t; k < NB; k += 256) ih[k] = 0;
    __syncthreads();
    int base = blockIdx.x * CH;
    for (int i = 0; i < CH; i += 256) {
        int e = base + i + t;
        if (e < E) atomicAdd(&ih[dst[e] >> 6], 1);
    }
    __syncthreads();
    for (int k = t; k < NB; k += 256) histmat[(size_t)blockIdx.x * NB + k] = ih[k];
}

// ONE block, 1024 threads: per-bucket exclusive prefix over chunks (in-place,
// coalesced, unroll-8), in-LDS scan of bucket totals -> bstart; zero gpart.
__global__ __launch_bounds__(1024) void k_scan(int* __restrict__ histmat,
                                               int* __restrict__ bstart,
                                               float* __restrict__ gpart,
                                               int NB, int nch, int E) {
    __shared__ int sc[1024];
    int t = threadIdx.x;
    int run = 0;
    if (t < NB) {
        int b = 0;
        for (; b + 8 <= nch; b += 8) {
            int v[8];
#pragma unroll
            for (int u = 0; u < 8; u++) v[u] = histmat[(size_t)(b + u) * NB + t];
#pragma unroll
            for (int u = 0; u < 8; u++) {
                int x = v[u];
                histmat[(size_t)(b + u) * NB + t] = run;
                run += x;
            }
        }
        for (; b < nch; b++) {
            int x = histmat[(size_t)b * NB + t];
            histmat[(size_t)b * NB + t] = run;
            run += x;
        }
    }
    sc[t] = (t < NB) ? run : 0;
    __syncthreads();
    for (int off = 1; off < 1024; off <<= 1) {
        int x = (t >= off) ? sc[t - off] : 0;
        __syncthreads();
        sc[t] += x;
        __syncthreads();
    }
    if (t < NB) bstart[t] = sc[t] - run;  // exclusive
    if (t == 0) bstart[NB] = E;
    if (t < 512) gpart[t] = 0.f;
}

__global__ __launch_bounds__(256) void k_bucket_scatter(const int* __restrict__ src,
                                                        const int* __restrict__ dst,
                                                        const int* __restrict__ histmat,
                                                        const int* __restrict__ bstart,
                                                        int* __restrict__ staged,
                                                        int E, int NB) {
    __shared__ int cur[MAXNB];
    int t = threadIdx.x;
    for (int k = t; k < NB; k += 256)
        cur[k] = bstart[k] + histmat[(size_t)blockIdx.x * NB + k];
    __syncthreads();
    int base = blockIdx.x * CH;
    for (int i = 0; i < CH; i += 256) {
        int e = base + i + t;
        if (e < E) {
            int d = dst[e];
            int pos = atomicAdd(&cur[d >> 6], 1);
            staged[pos] = (src[e] << 6) | (d & 63);  // n<=65536 -> fits
        }
    }
}

// Per-bucket degree count -> dinv. Tiny kernel (R18's fused phase, un-fused).
__global__ __launch_bounds__(256) void k_dinv(const int* __restrict__ staged,
                                              const int* __restrict__ bstart,
                                              float* __restrict__ dinv, int n) {
    __shared__ int cnt[64];
    int t = threadIdx.x, kb = blockIdx.x;
    if (t < 64) cnt[t] = 0;
    __syncthreads();
    int beg = bstart[kb], end = bstart[kb + 1];
    for (int e = beg + t; e < end; e += 256) atomicAdd(&cnt[staged[e] & 63], 1);
    __syncthreads();
    if (t < 64) {
        int node = kb * 64 + t;
        if (node < n) dinv[node] = 1.0f / sqrtf((float)(cnt[t] + 1));  // + self
    }
}

// y1[i,:] = dinv[i] * (X[i,:] @ W) stored as bf16 rows. R12-proven (3125 blk).
__global__ __launch_bounds__(256) void k_gemm_scale(const float* __restrict__ X,
                                                    const float* __restrict__ W,
                                                    const float* __restrict__ dinv,
                                                    unsigned short* __restrict__ Y, int n) {
    __shared__ float Ws[64 * 64];
    __shared__ float xs[16][64];
    int t = threadIdx.x, w = t >> 6, f = t & 63;
    const float4* W4 = (const float4*)W;
    float4* Ws4 = (float4*)Ws;
#pragma unroll
    for (int j = 0; j < 4; j++) Ws4[t + 256 * j] = W4[t + 256 * j];
    int r0 = blockIdx.x * 16;
#pragma unroll
    for (int i = 0; i < 4; i++) {
        int r = r0 + w * 4 + i;
        xs[w * 4 + i][f] = (r < n) ? X[(size_t)r * 64 + f] : 0.f;
    }
    __syncthreads();
    float acc[4] = {0.f, 0.f, 0.f, 0.f};
#pragma unroll 8
    for (int k = 0; k < 64; k++) {
        float wv = Ws[k * 64 + f];
#pragma unroll
        for (int i = 0; i < 4; i++) acc[i] += xs[w * 4 + i][k] * wv;
    }
#pragma unroll
    for (int i = 0; i < 4; i++) {
        int r = r0 + w * 4 + i;
        if (r < n) Y[(size_t)r * 64 + f] = f2bf(dinv[r] * acc[i]);
    }
}

// Layer-1 aggregate (edge-parallel, native int ds_add) + fused GEMM2.
// 512 threads = 8 waves (R18 was 4; ~24 waves/CU for latency hiding).
// accL: feature f=4c+j of node dl at col m=16j+c (row stride 68 ints).
__global__ __launch_bounds__(512) void k_agg1(const unsigned short* __restrict__ Yin,
                                              const float* __restrict__ dinv,
                                              const float* __restrict__ b1,
                                              const int* __restrict__ staged,
                                              const int* __restrict__ bstart,
                                              const float* __restrict__ W2,
                                              unsigned short* __restrict__ Yout, int n) {
    __shared__ int accL[64 * 68];   // 17408 B
    __shared__ float Ws[64 * 64];   // 16 KB, fm-swizzled rows of W2
    __shared__ float dvs[64];
    float* accF = (float*)accL;
    int t = threadIdx.x, w = t >> 6, l = t & 63;
    int kb = blockIdx.x;
    {
        int4* a4 = (int4*)accL;
        int4 z = make_int4(0, 0, 0, 0);
        for (int i = t; i < 64 * 17; i += 512) a4[i] = z;
        int m = t >> 3, seg = t & 7;
        int fm = ((m & 15) << 2) | (m >> 4);
        const float4* W24 = (const float4*)W2;
        float4* Ws4 = (float4*)Ws;
#pragma unroll
        for (int k = 0; k < 2; k++) Ws4[m * 16 + seg * 2 + k] = W24[fm * 16 + seg * 2 + k];
        if (t < 64) {
            int node = kb * 64 + t;
            dvs[t] = (node < n) ? dinv[node] : 0.f;
        }
    }
    __syncthreads();
    // ---- stream slab: slot S (32 slots of 16 threads) -> 128-edge windows
    int beg = bstart[kb], end = bstart[kb + 1];
    int c = t & 15;
    int S = t >> 4;  // 0..31
    const ushort4* Y4 = (const ushort4*)Yin;
    int eb = beg + S * 4;
    int pk[4];
#pragma unroll
    for (int u = 0; u < 4; u++) pk[u] = (eb + u < end) ? staged[eb + u] : -1;
    for (; eb < end;) {
        int en = eb + 128;
        int pn[4];
#pragma unroll
        for (int u = 0; u < 4; u++) pn[u] = (en + u < end) ? staged[en + u] : -1;
#pragma unroll
        for (int u = 0; u < 4; u++) {
            int p = pk[u];
            if (p >= 0) {
                int s = p >> 6, dl = p & 63;
                ushort4 v = Y4[(size_t)s * 16 + c];
                int* ap = &accL[dl * 68 + c];
                atomicAdd(ap + 0,  __float2int_rn(bf2f(v.x) * SCL));
                atomicAdd(ap + 16, __float2int_rn(bf2f(v.y) * SCL));
                atomicAdd(ap + 32, __float2int_rn(bf2f(v.z) * SCL));
                atomicAdd(ap + 48, __float2int_rn(bf2f(v.w) * SCL));
            }
        }
#pragma unroll
        for (int u = 0; u < 4; u++) pk[u] = pn[u];
        eb = en;
    }
    __syncthreads();
    // ---- Phase A: in-place int -> h' = dv * relu(dv*(acc+self) + b1)
    {
        int r = t >> 3, g8 = t & 7;   // thread: row r, cols g8*8..g8*8+7
        int node = kb * 64 + r;
        float dv = dvs[r];
        bool valid = node < n;
#pragma unroll
        for (int jj = 0; jj < 8; jj++) {
            int m = g8 * 8 + jj;
            int fm = ((m & 15) << 2) | (m >> 4);
            float aggv = (float)accL[r * 68 + m] * INVSCL;
            float self = valid ? bf2f(Yin[(size_t)node * 64 + fm]) : 0.f;
            float hv = fmaxf(dv * (aggv + self) + b1[fm], 0.f);
            accF[r * 68 + m] = valid ? dv * hv : 0.f;
        }
    }
    __syncthreads();
    // ---- Phase B: GEMM2. wave w: rows w*8..w*8+7; lane l = out feature.
    float acc2[8];
#pragma unroll
    for (int r = 0; r < 8; r++) acc2[r] = 0.f;
    for (int q = 0; q < 16; q++) {
        float wv0 = Ws[(4 * q + 0) * 64 + l];
        float wv1 = Ws[(4 * q + 1) * 64 + l];
        float wv2 = Ws[(4 * q + 2) * 64 + l];
        float wv3 = Ws[(4 * q + 3) * 64 + l];
#pragma unroll
        for (int r = 0; r < 8; r++) {
            float4 h4 = *(const float4*)&accF[(w * 8 + r) * 68 + 4 * q];
            acc2[r] += h4.x * wv0 + h4.y * wv1 + h4.z * wv2 + h4.w * wv3;
        }
    }
#pragma unroll
    for (int r = 0; r < 8; r++) {
        int node = kb * 64 + w * 8 + r;
        if (node < n) Yout[(size_t)node * 64 + l] = f2bf(acc2[r]);
    }
}

// Layer-2 aggregate (int ds_add) + mean folded into 8-way gpart atomics
// (782 x 64 = 50k global atomics, R13-proven scale). 512 threads.
__global__ __launch_bounds__(512) void k_agg2(const unsigned short* __restrict__ Yin,
                                              const float* __restrict__ dinv,
                                              const float* __restrict__ b2,
                                              const int* __restrict__ staged,
                                              const int* __restrict__ bstart,
                                              float* __restrict__ gpart, int n) {
    __shared__ int accL[64 * 68];
    __shared__ float dvs[64];
    __shared__ float part[8][64];
    int t = threadIdx.x, w = t >> 6, l = t & 63;
    int kb = blockIdx.x;
    {
        int4* a4 = (int4*)accL;
        int4 z = make_int4(0, 0, 0, 0);
        for (int i = t; i < 64 * 17; i += 512) a4[i] = z;
        if (t < 64) {
            int node = kb * 64 + t;
            dvs[t] = (node < n) ? dinv[node] : 0.f;
        }
    }
    __syncthreads();
    int beg = bstart[kb], end = bstart[kb + 1];
    int c = t & 15;
    int S = t >> 4;
    const ushort4* Y4 = (const ushort4*)Yin;
    int eb = beg + S * 4;
    int pk[4];
#pragma unroll
    for (int u = 0; u < 4; u++) pk[u] = (eb + u < end) ? staged[eb + u] : -1;
    for (; eb < end;) {
        int en = eb + 128;
        int pn[4];
#pragma unroll
        for (int u = 0; u < 4; u++) pn[u] = (en + u < end) ? staged[en + u] : -1;
#pragma unroll
        for (int u = 0; u < 4; u++) {
            int p = pk[u];
            if (p >= 0) {
                int s = p >> 6, dl = p & 63;
                ushort4 v = Y4[(size_t)s * 16 + c];
                int* ap = &accL[dl * 68 + c];
                atomicAdd(ap + 0,  __float2int_rn(bf2f(v.x) * SCL));
                atomicAdd(ap + 16, __float2int_rn(bf2f(v.y) * SCL));
                atomicAdd(ap + 32, __float2int_rn(bf2f(v.z) * SCL));
                atomicAdd(ap + 48, __float2int_rn(bf2f(v.w) * SCL));
            }
        }
#pragma unroll
        for (int u = 0; u < 4; u++) pk[u] = pn[u];
        eb = en;
    }
    __syncthreads();
    int m = l;
    int fm = ((m & 15) << 2) | (m >> 4);
    float bb = b2[fm];
    float local = 0.f;
#pragma unroll
    for (int i = 0; i < 8; i++) {
        int r = w * 8 + i;
        int node = kb * 64 + r;
        if (node < n) {
            float dv = dvs[r];
            float aggv = (float)accL[r * 68 + m] * INVSCL;
            float self = bf2f(Yin[(size_t)node * 64 + fm]);
            local += fmaxf(dv * (aggv + self) + bb, 0.f);
        }
    }
    part[w][m] = local;
    __syncthreads();
    if (t < 64) {
        float tot = 0.f;
#pragma unroll
        for (int r = 0; r < 8; r++) tot += part[r][t];
        int fm2 = ((t & 15) << 2) | (t >> 4);
        atomicAdd(&gpart[((kb & 7) << 6) + fm2], tot);
    }
}

__global__ void k_readout(const float* __restrict__ gpart, const float* __restrict__ Wr,
                          const float* __restrict__ br, float* __restrict__ out,
                          float invn) {
    __shared__ float gl[64];
    int t = threadIdx.x;
    if (t < 64) {
        float s = 0.f;
#pragma unroll
        for (int j = 0; j < 8; j++) s += gpart[j * 64 + t];
        gl[t] = s * invn;
    }
    __syncthreads();
    float acc = br[t];
#pragma unroll
    for (int k = 0; k < 64; k++) acc += gl[k] * Wr[k * 128 + t];
    out[t] = acc;
}

extern "C" void kernel_launch(void* const* d_in, const int* in_sizes, int n_in,
                              void* d_out, int out_size, void* d_ws, size_t ws_size,
                              hipStream_t stream) {
    const float* x  = (const float*)d_in[0];
    const int*   ei = (const int*)d_in[1];   // int32 on device (JAX x64 off)
    const float* W1 = (const float*)d_in[2];
    const float* b1 = (const float*)d_in[3];
    const float* W2 = (const float*)d_in[4];
    const float* b2 = (const float*)d_in[5];
    const float* Wr = (const float*)d_in[6];
    const float* br = (const float*)d_in[7];
    float* out = (float*)d_out;

    int n = in_sizes[0] / 64;   // 50000
    int E = in_sizes[1] / 2;    // 800000
    const int* src = ei;
    const int* dst = ei + E;

    int NB  = (n + 63) / 64;       // 782 buckets of 64 nodes
    int nch = (E + CH - 1) / CH;   // 196 chunks

    // workspace layout (~17 MB)
    char* p = (char*)d_ws;
    unsigned short* y1 = (unsigned short*)p; p += (size_t)n * 64 * sizeof(unsigned short);
    unsigned short* y2 = (unsigned short*)p; p += (size_t)n * 64 * sizeof(unsigned short);
    float* dinv = (float*)p;   p += (size_t)n * sizeof(float);
    float* gpart = (float*)p;  p += 512 * sizeof(float);
    int* staged = (int*)p;     p += (size_t)E * sizeof(int);
    int* histmat = (int*)p;    p += (size_t)nch * NB * sizeof(int);
    int* bstart = (int*)p;     p += (size_t)(NB + 1) * sizeof(int);

    k_bucket_hist<<<nch, 256, 0, stream>>>(dst, histmat, E, NB);
    k_scan<<<1, 1024, 0, stream>>>(histmat, bstart, gpart, NB, nch, E);
    k_bucket_scatter<<<nch, 256, 0, stream>>>(src, dst, histmat, bstart, staged, E, NB);
    k_dinv<<<NB, 256, 0, stream>>>(staged, bstart, dinv, n);
    k_gemm_scale<<<(n + 15) / 16, 256, 0, stream>>>(x, W1, dinv, y1, n);
    k_agg1<<<NB, 512, 0, stream>>>(y1, dinv, b1, staged, bstart, W2, y2, n);
    k_agg2<<<NB, 512, 0, stream>>>(y2, dinv, b2, staged, bstart, gpart, n);
    k_readout<<<1, 128, 0, stream>>>(gpart, Wr, br, out, 1.0f / (float)n);
}

// Round 8
// 271.278 us; speedup vs baseline: 1.6654x; 1.6654x over previous
//
#include <hip/hip_runtime.h>
#include <math.h>

// SimpleGCN R20 = R12 (measured 230.9us, best) + three mechanism-clear deltas.
//  - R19 post-mortem: 512-thread edge-parallel agg = 900MB phantom traffic,
//    290us. Five structural agg mutations (R13-R19) all lost to R12's
//    wave-per-node gather; agg ~50us is gather-bound (random 128B rows) and
//    epilogue-insensitive (pool ~= fuse). Agg kernels frozen at R12 form.
//  - Delta 1: gemm_scale inner loop restructured: 16 iters x {4 Ws b32
//    (lane-contig) + 4 broadcast float4 xs reads} = 128 LDS ops/lane
//    vs 320 (was 64 x {1 Ws + 4 scalar xs}). LDS-throughput bound -> ~22us.
//  - Delta 2: CH 4096->2048: hist/scatter 196->391 blocks (>1/CU coverage).
//  - Delta 3: agg_fuse post-park __syncthreads removed (hs wave-private,
//    same-wave DS ordering via lgkmcnt; R17 validated the pattern).
//  - 9 dispatches, preprocessing/agg/mean/readout otherwise R12 verbatim.

#define CH 2048    // edges per chunk-block in hist/scatter
#define MAXNB 1024 // NB = ceil(n/64) <= 1024 (n <= 65536)

__device__ __forceinline__ float bf2f(unsigned short u) {
    return __uint_as_float(((unsigned)u) << 16);
}
__device__ __forceinline__ unsigned short f2bf(float x) {
    unsigned b = __float_as_uint(x);
    return (unsigned short)((b + 0x7FFF + ((b >> 16) & 1)) >> 16);  // RNE
}

__global__ __launch_bounds__(256) void k_bucket_hist(const int* __restrict__ dst,
                                                     int* __restrict__ histmat,
                                                     int E, int NB) {
    __shared__ int ih[MAXNB];
    int t = threadIdx.x;
    for (int k = t; k < NB; k += 256) ih[k] = 0;
    __syncthreads();
    int base = blockIdx.x * CH;
    for (int i = 0; i < CH; i += 256) {
        int e = base + i + t;
        if (e < E) atomicAdd(&ih[dst[e] >> 6], 1);
    }
    __syncthreads();
    for (int k = t; k < NB; k += 256) histmat[(size_t)blockIdx.x * NB + k] = ih[k];
}

// ONE block, 1024 threads (thread = bucket, NB<=1024): per-bucket exclusive
// prefix over chunks (in-place in histmat, coalesced, unroll-8), then an
// in-LDS Hillis-Steele scan of bucket totals -> bstart. Also zeroes g.
__global__ __launch_bounds__(1024) void k_scan(int* __restrict__ histmat,
                                               int* __restrict__ bstart,
                                               int* __restrict__ offsets,
                                               float* __restrict__ g,
                                               int NB, int nch, int E, int n) {
    __shared__ int sc[1024];
    int t = threadIdx.x;
    int run = 0;
    if (t < NB) {
        int b = 0;
        for (; b + 8 <= nch; b += 8) {
            int v[8];
#pragma unroll
            for (int u = 0; u < 8; u++) v[u] = histmat[(size_t)(b + u) * NB + t];
#pragma unroll
            for (int u = 0; u < 8; u++) {
                int x = v[u];
                histmat[(size_t)(b + u) * NB + t] = run;
                run += x;
            }
        }
        for (; b < nch; b++) {
            int x = histmat[(size_t)b * NB + t];
            histmat[(size_t)b * NB + t] = run;
            run += x;
        }
    }
    sc[t] = (t < NB) ? run : 0;
    __syncthreads();
    for (int off = 1; off < 1024; off <<= 1) {
        int x = (t >= off) ? sc[t - off] : 0;
        __syncthreads();
        sc[t] += x;
        __syncthreads();
    }
    if (t < NB) bstart[t] = sc[t] - run;  // exclusive
    if (t == 0) { bstart[NB] = E; offsets[n] = E; }
    if (t < 64) g[t] = 0.f;
}

__global__ __launch_bounds__(256) void k_bucket_scatter(const int* __restrict__ src,
                                                        const int* __restrict__ dst,
                                                        const int* __restrict__ histmat,
                                                        const int* __restrict__ bstart,
                                                        int* __restrict__ staged,
                                                        int E, int NB) {
    __shared__ int cur[MAXNB];
    int t = threadIdx.x;
    for (int k = t; k < NB; k += 256)
        cur[k] = bstart[k] + histmat[(size_t)blockIdx.x * NB + k];
    __syncthreads();
    int base = blockIdx.x * CH;
    for (int i = 0; i < CH; i += 256) {
        int e = base + i + t;
        if (e < E) {
            int d = dst[e];
            int pos = atomicAdd(&cur[d >> 6], 1);
            staged[pos] = (src[e] << 6) | (d & 63);  // n<=65536 -> fits
        }
    }
}

// one block per bucket: counting-sort staged run into node-granular ushort
// CSR; emit per-node offsets + dinv.
__global__ __launch_bounds__(256) void k_local_sort(const int* __restrict__ staged,
                                                    const int* __restrict__ bstart,
                                                    unsigned short* __restrict__ csr,
                                                    int* __restrict__ offsets,
                                                    float* __restrict__ dinv, int n) {
    __shared__ int cnt[64];
    __shared__ int pos[64];
    __shared__ int cur[64];
    int t = threadIdx.x;
    if (t < 64) cnt[t] = 0;
    __syncthreads();
    int k = blockIdx.x;
    int beg = bstart[k], end = bstart[k + 1];
    for (int e = beg + t; e < end; e += 256) atomicAdd(&cnt[staged[e] & 63], 1);
    __syncthreads();
    if (t == 0) {
        int run = 0;
        for (int i = 0; i < 64; i++) { pos[i] = run; run += cnt[i]; }
    }
    __syncthreads();
    if (t < 64) {
        cur[t] = pos[t];
        int node = k * 64 + t;
        if (node < n) {
            offsets[node] = beg + pos[t];
            dinv[node] = 1.0f / sqrtf((float)(cnt[t] + 1));  // + self-loop
        }
    }
    __syncthreads();
    for (int e = beg + t; e < end; e += 256) {
        int pk = staged[e];
        int p = atomicAdd(&cur[pk & 63], 1);
        csr[beg + p] = (unsigned short)(pk >> 6);
    }
}

// y1[i,:] = dinv[i] * (X[i,:] @ W) stored as bf16 rows (128B = 1 line).
// R20: inner loop = 16 q-iters x {4 Ws b32 (lane-contig) + 4 bcast float4 xs}
// -> 128 LDS ops/lane vs R12's 320 (was LDS-throughput bound).
__global__ __launch_bounds__(256) void k_gemm_scale(const float* __restrict__ X,
                                                    const float* __restrict__ W,
                                                    const float* __restrict__ dinv,
                                                    unsigned short* __restrict__ Y, int n) {
    __shared__ float Ws[64 * 64];
    __shared__ float xs[16][64];
    int t = threadIdx.x, w = t >> 6, f = t & 63;
    const float4* W4 = (const float4*)W;
    float4* Ws4 = (float4*)Ws;
#pragma unroll
    for (int j = 0; j < 4; j++) Ws4[t + 256 * j] = W4[t + 256 * j];
    int r0 = blockIdx.x * 16;
#pragma unroll
    for (int i = 0; i < 4; i++) {
        int r = r0 + w * 4 + i;
        xs[w * 4 + i][f] = (r < n) ? X[(size_t)r * 64 + f] : 0.f;
    }
    __syncthreads();
    float acc[4] = {0.f, 0.f, 0.f, 0.f};
#pragma unroll
    for (int q = 0; q < 16; q++) {
        float wv0 = Ws[(4 * q + 0) * 64 + f];
        float wv1 = Ws[(4 * q + 1) * 64 + f];
        float wv2 = Ws[(4 * q + 2) * 64 + f];
        float wv3 = Ws[(4 * q + 3) * 64 + f];
#pragma unroll
        for (int i = 0; i < 4; i++) {
            float4 xv = *(const float4*)&xs[w * 4 + i][4 * q];  // broadcast
            acc[i] += xv.x * wv0 + xv.y * wv1 + xv.z * wv2 + xv.w * wv3;
        }
    }
#pragma unroll
    for (int i = 0; i < 4; i++) {
        int r = r0 + w * 4 + i;
        if (r < n) Y[(size_t)r * 64 + f] = f2bf(dinv[r] * acc[i]);
    }
}

// Layer-1 aggregate + fused GEMM2. Gather identical to R12: one wave per
// node (beg/end wave-uniform), lane=(q,c), ushort4 slot loads, unroll-4,
// shfl_xor(16,32) reduce, fp32 h. Epilogue: q==0 lanes park h row in LDS
// (wave-private hs[w] -> NO barrier needed, same-wave lgkmcnt ordering),
// lane l computes y2[node][l] = dinv*(h @ W2[:,l]) from LDS W2.
__global__ __launch_bounds__(256) void k_agg_fuse(const unsigned short* __restrict__ Y,
                                                  const float* __restrict__ dinv,
                                                  const float* __restrict__ bias,
                                                  const int* __restrict__ offsets,
                                                  const unsigned short* __restrict__ csr,
                                                  const float* __restrict__ W2,
                                                  unsigned short* __restrict__ Yout, int n) {
    __shared__ float Ws[64 * 64];   // 16 KB
    __shared__ float hs[4][64];     // 1 KB
    const ushort4* Y4 = (const ushort4*)Y;
    int t = threadIdx.x, w = t >> 6, l = t & 63;
    int q = l >> 4, c = l & 15;
    {
        const float4* W4 = (const float4*)W2;
        float4* Ws4 = (float4*)Ws;
#pragma unroll
        for (int j = 0; j < 4; j++) Ws4[t + 256 * j] = W4[t + 256 * j];
    }
    __syncthreads();  // Ws visible to all waves
    int node = blockIdx.x * 4 + w;
    bool valid = node < n;
    float4 hval = make_float4(0.f, 0.f, 0.f, 0.f);
    float dv = 0.f;
    if (valid) {
        float4 acc = make_float4(0.f, 0.f, 0.f, 0.f);
        if (q == 0) {  // self-loop term
            ushort4 u = Y4[(size_t)node * 16 + c];
            acc = make_float4(bf2f(u.x), bf2f(u.y), bf2f(u.z), bf2f(u.w));
        }
        int beg = offsets[node], end = offsets[node + 1];
        for (int j = beg + q; j < end; j += 16) {
#pragma unroll
            for (int u = 0; u < 4; u++) {
                int jj = j + 4 * u;
                if (jj < end) {
                    int s = csr[jj];                     // uniform within slot
                    ushort4 v = Y4[(size_t)s * 16 + c];  // 16 lanes x 8B = row
                    acc.x += bf2f(v.x); acc.y += bf2f(v.y);
                    acc.z += bf2f(v.z); acc.w += bf2f(v.w);
                }
            }
        }
#pragma unroll
        for (int m = 16; m <= 32; m <<= 1) {
            acc.x += __shfl_xor(acc.x, m);
            acc.y += __shfl_xor(acc.y, m);
            acc.z += __shfl_xor(acc.z, m);
            acc.w += __shfl_xor(acc.w, m);
        }
        dv = dinv[node];
        float4 b4 = ((const float4*)bias)[c];
        hval.x = fmaxf(dv * acc.x + b4.x, 0.f);
        hval.y = fmaxf(dv * acc.y + b4.y, 0.f);
        hval.z = fmaxf(dv * acc.z + b4.z, 0.f);
        hval.w = fmaxf(dv * acc.w + b4.w, 0.f);
    }
    if (q == 0) ((float4*)hs[w])[c] = hval;  // zeros if invalid
    // hs[w] is wave-private: same-wave DS RAW ordered by lgkmcnt, no barrier.
    if (valid) {
        float acc2 = 0.f;
#pragma unroll
        for (int m = 0; m < 16; m++) {
            float4 h4 = ((const float4*)hs[w])[m];   // wave-broadcast
            acc2 += h4.x * Ws[(4 * m + 0) * 64 + l] + h4.y * Ws[(4 * m + 1) * 64 + l]
                  + h4.z * Ws[(4 * m + 2) * 64 + l] + h4.w * Ws[(4 * m + 3) * 64 + l];
        }
        Yout[(size_t)node * 64 + l] = f2bf(dv * acc2);
    }
}

// Layer-2 aggregate + per-block partial mean rows (R12 POOL path).
__global__ __launch_bounds__(256) void k_agg_pool(const unsigned short* __restrict__ Y,
                                                  const float* __restrict__ dinv,
                                                  const float* __restrict__ bias,
                                                  const int* __restrict__ offsets,
                                                  const unsigned short* __restrict__ csr,
                                                  float* __restrict__ pbuf, int n) {
    __shared__ float4 sm4[4][16];
    const ushort4* Y4 = (const ushort4*)Y;
    int t = threadIdx.x, w = t >> 6, l = t & 63;
    int q = l >> 4, c = l & 15;
    int node = blockIdx.x * 4 + w;
    bool valid = node < n;
    float4 hval = make_float4(0.f, 0.f, 0.f, 0.f);
    if (valid) {
        float4 acc = make_float4(0.f, 0.f, 0.f, 0.f);
        if (q == 0) {
            ushort4 u = Y4[(size_t)node * 16 + c];
            acc = make_float4(bf2f(u.x), bf2f(u.y), bf2f(u.z), bf2f(u.w));
        }
        int beg = offsets[node], end = offsets[node + 1];
        for (int j = beg + q; j < end; j += 16) {
#pragma unroll
            for (int u = 0; u < 4; u++) {
                int jj = j + 4 * u;
                if (jj < end) {
                    int s = csr[jj];
                    ushort4 v = Y4[(size_t)s * 16 + c];
                    acc.x += bf2f(v.x); acc.y += bf2f(v.y);
                    acc.z += bf2f(v.z); acc.w += bf2f(v.w);
                }
            }
        }
#pragma unroll
        for (int m = 16; m <= 32; m <<= 1) {
            acc.x += __shfl_xor(acc.x, m);
            acc.y += __shfl_xor(acc.y, m);
            acc.z += __shfl_xor(acc.z, m);
            acc.w += __shfl_xor(acc.w, m);
        }
        float dv = dinv[node];
        float4 b4 = ((const float4*)bias)[c];
        hval.x = fmaxf(dv * acc.x + b4.x, 0.f);
        hval.y = fmaxf(dv * acc.y + b4.y, 0.f);
        hval.z = fmaxf(dv * acc.z + b4.z, 0.f);
        hval.w = fmaxf(dv * acc.w + b4.w, 0.f);
    }
    if (q == 0) sm4[w][c] = valid ? hval : make_float4(0.f, 0.f, 0.f, 0.f);
    __syncthreads();
    if (t < 16) {
        float4 a = sm4[0][t], b = sm4[1][t], d = sm4[2][t], e = sm4[3][t];
        float4 s;
        s.x = (a.x + b.x) + (d.x + e.x);
        s.y = (a.y + b.y) + (d.y + e.y);
        s.z = (a.z + b.z) + (d.z + e.z);
        s.w = (a.w + b.w) + (d.w + e.w);
        ((float4*)pbuf)[(size_t)blockIdx.x * 16 + t] = s;
    }
}

__global__ void k_mean_final(const float* __restrict__ pbuf, float* __restrict__ g,
                             int nrows) {
    __shared__ float part[256];
    int t = threadIdx.x, w = t >> 6, f = t & 63;
    float local = 0.f;
    for (int r = blockIdx.x * 4 + w; r < nrows; r += gridDim.x * 4)
        local += pbuf[(size_t)r * 64 + f];
    part[t] = local;
    __syncthreads();
    if (w == 0) {
        float tot = part[f] + part[64 + f] + part[128 + f] + part[192 + f];
        atomicAdd(&g[f], tot);
    }
}

__global__ void k_readout(const float* __restrict__ g, const float* __restrict__ Wr,
                          const float* __restrict__ br, float* __restrict__ out,
                          float invn) {
    __shared__ float gl[64];
    int t = threadIdx.x;
    if (t < 64) gl[t] = g[t] * invn;
    __syncthreads();
    float acc = br[t];
#pragma unroll
    for (int k = 0; k < 64; k++) acc += gl[k] * Wr[k * 128 + t];
    out[t] = acc;
}

extern "C" void kernel_launch(void* const* d_in, const int* in_sizes, int n_in,
                              void* d_out, int out_size, void* d_ws, size_t ws_size,
                              hipStream_t stream) {
    const float* x  = (const float*)d_in[0];
    const int*   ei = (const int*)d_in[1];   // int32 on device (JAX x64 off)
    const float* W1 = (const float*)d_in[2];
    const float* b1 = (const float*)d_in[3];
    const float* W2 = (const float*)d_in[4];
    const float* b2 = (const float*)d_in[5];
    const float* Wr = (const float*)d_in[6];
    const float* br = (const float*)d_in[7];
    float* out = (float*)d_out;

    int n = in_sizes[0] / 64;   // 50000
    int E = in_sizes[1] / 2;    // 800000
    const int* src = ei;
    const int* dst = ei + E;

    int NB  = (n + 63) / 64;       // 782 buckets of 64 nodes
    int nch = (E + CH - 1) / CH;   // 391 chunks (CH=2048)

    // workspace layout (~20 MB)
    char* p = (char*)d_ws;
    unsigned short* y1 = (unsigned short*)p; p += (size_t)n * 64 * sizeof(unsigned short);
    unsigned short* y2 = (unsigned short*)p; p += (size_t)n * 64 * sizeof(unsigned short);
    float* pbuf = (float*)p;   p += (size_t)((n + 3) / 4) * 64 * sizeof(float);
    float* dinv = (float*)p;   p += (size_t)n * sizeof(float);
    float* g = (float*)p;      p += 64 * sizeof(float);
    int* staged = (int*)p;     p += (size_t)E * sizeof(int);
    int* offsets = (int*)p;    p += (size_t)(n + 1) * sizeof(int);
    int* histmat = (int*)p;    p += (size_t)nch * NB * sizeof(int);
    int* bstart = (int*)p;     p += (size_t)(NB + 1) * sizeof(int);
    unsigned short* csr = (unsigned short*)p; p += (size_t)E * sizeof(unsigned short);

    k_bucket_hist<<<nch, 256, 0, stream>>>(dst, histmat, E, NB);
    k_scan<<<1, 1024, 0, stream>>>(histmat, bstart, offsets, g, NB, nch, E, n);
    k_bucket_scatter<<<nch, 256, 0, stream>>>(src, dst, histmat, bstart, staged, E, NB);
    k_local_sort<<<NB, 256, 0, stream>>>(staged, bstart, csr, offsets, dinv, n);

    int gb = (n + 3) / 4;  // 12500 aggregate blocks (one wave per node)
    k_gemm_scale<<<(n + 15) / 16, 256, 0, stream>>>(x, W1, dinv, y1, n);
    k_agg_fuse<<<gb, 256, 0, stream>>>(y1, dinv, b1, offsets, csr, W2, y2, n);
    k_agg_pool<<<gb, 256, 0, stream>>>(y2, dinv, b2, offsets, csr, pbuf, n);

    k_mean_final<<<64, 256, 0, stream>>>(pbuf, g, gb);
    k_readout<<<1, 128, 0, stream>>>(g, Wr, br, out, 1.0f / (float)n);
}